// Round 6
// baseline (344.899 us; speedup 1.0000x reference)
//
#include <hip/hip_runtime.h>
#include <math.h>

#define NN 100000
#define NE 1600000
#define NT (NE + NN)   // 1700000 edges incl. self-loops
#define DD 128
#define NB 500          // dst buckets
#define BR 200          // node range per bucket (NB*BR == NN)
#define NSUB 8          // sub-buckets (keyed on blockIdx&7 ~ XCD id)
#define SCAP 768        // per-sub capacity (mean 400, sigma 20 -> 18 sigma headroom)
#define BCAP (NSUB*SCAP) // 6144 per bucket
#define BMAGIC 21474837u // ceil(2^32/200); exact for d < 100000

typedef unsigned int uint;

// round-to-nearest-even fp32 -> bf16 (16-bit payload in a uint)
__device__ __forceinline__ uint bfr(float f){
  uint u = __float_as_uint(f);
  return (u + 0x7FFFu + ((u >> 16) & 1u)) >> 16;
}
__device__ __forceinline__ uint pk2(float a, float b){
  return (bfr(a) & 0xFFFFu) | (bfr(b) << 16);
}

// ---------------- preprocessing: LDS-local bucket sort, XCD-local sub-counters ----------------

// pass 1: scatter edges into (bucket, sub) regions; entry = src(17b) | d_local(8b)<<17
// counters bcnt[(b*NSUB+sub)*16] each own a 64B line; sub = blockIdx&7 keeps
// same-line atomics XCD-local (round-robin dispatch) and cuts per-line traffic 8x.
__global__ __launch_bounds__(256) void k_bucket(const int* __restrict__ ei,
    int* __restrict__ bcnt, uint* __restrict__ bedge){
  int i = blockIdx.x*256 + threadIdx.x;
  int sub = blockIdx.x & (NSUB-1);
  if (i < NE){
    uint s = (uint)ei[i];
    uint d = (uint)ei[NE + i];
    uint b = __umulhi(d, BMAGIC);          // d / 200
    uint dl = d - b*BR;
    int p = atomicAdd(&bcnt[(b*NSUB + sub)*16], 1);
    bedge[(size_t)b*BCAP + sub*SCAP + p] = s | (dl << 17);
  }
}

// pass 2: per-bucket LDS degree count -> coalesced deg/dis writes
__global__ __launch_bounds__(256) void k_deg(const int* __restrict__ bcnt,
    const uint* __restrict__ bedge, int* __restrict__ deg, float* __restrict__ dis){
  __shared__ int cl[BR];
  int b = blockIdx.x, t = threadIdx.x;
  if (t < BR) cl[t] = 0;
  __syncthreads();
  for (int sub = 0; sub < NSUB; ++sub){
    int cs = bcnt[(b*NSUB + sub)*16];
    for (int e = t; e < cs; e += 256){
      uint u = bedge[(size_t)b*BCAP + sub*SCAP + e];
      atomicAdd(&cl[u >> 17], 1);
    }
  }
  __syncthreads();
  if (t < BR){
    int n = b*BR + t;
    int dg = cl[t];
    deg[n] = dg;                           // in-degree excl self-loop
    dis[n] = rsqrtf((float)(dg + 1));
  }
}

// pass 3: per-bucket CSR build: LDS count + scan, norms, contiguous es/rowptr writes
__global__ __launch_bounds__(256) void k_build(const int* __restrict__ bcnt,
    const uint* __restrict__ bedge, const float* __restrict__ dis,
    int* __restrict__ rowptr, uint* __restrict__ es){
  __shared__ uint  eL[BCAP];
  __shared__ int   cl[BR];
  __shared__ int   fl[BR];
  __shared__ float dl_[BR];
  __shared__ int   pf[256];
  __shared__ int   red[256];
  int b = blockIdx.x, t = threadIdx.x;

  // base = sum over all subs of previous buckets + BR*b (self-loops)
  int part = 0;
  for (int i = t; i < b*NSUB; i += 256) part += bcnt[i*16];
  red[t] = part;
  __syncthreads();
  for (int off = 128; off > 0; off >>= 1){
    if (t < off) red[t] += red[t + off];
    __syncthreads();
  }
  int base = red[0] + b*BR;

  if (t < BR){ cl[t] = 0; fl[t] = 0; }
  __syncthreads();
  int cnt = 0;                             // uniform running offset into eL
  for (int sub = 0; sub < NSUB; ++sub){
    int cs = bcnt[(b*NSUB + sub)*16];      // uniform scalar load
    for (int e = t; e < cs; e += 256){
      uint u = bedge[(size_t)b*BCAP + sub*SCAP + e];
      eL[cnt + e] = u;
      atomicAdd(&cl[u >> 17], 1);
    }
    cnt += cs;
  }
  __syncthreads();
  // inclusive scan over (cl[i]+1)
  int v = (t < BR) ? (cl[t] + 1) : 0;
  pf[t] = v;
  __syncthreads();
  for (int off = 1; off < 256; off <<= 1){
    int a = (t >= off) ? pf[t-off] : 0;
    __syncthreads();
    pf[t] += a;
    __syncthreads();
  }
  if (t < BR){
    int n  = b*BR + t;
    int p0 = base + pf[t] - v;             // exclusive prefix
    rowptr[n] = p0;
    float dn = dis[n];
    dl_[t] = dn;
    es[p0 + cl[t]] = (uint)n | ((bfr(dn*dn) & 0x7FFFu) << 17);  // self-loop last
  }
  __syncthreads();
  for (int e = t; e < cnt; e += 256){
    uint u = eL[e];
    uint s = u & 0x1FFFFu;
    int  dloc = u >> 17;
    int  q  = atomicAdd(&fl[dloc], 1);
    int  p0 = base + pf[dloc] - (cl[dloc] + 1);
    es[p0 + q] = s | ((bfr(dis[s] * dl_[dloc]) & 0x7FFFu) << 17);
  }
}

// ---------------- GEMM -> bf16: Y[nrows,128](bf16) = X[nrows,128] @ W[128,128] ----------------
// 128 rows/block, 256 threads, 8x8 register tile/thread, quarter-K phases.
// LDS: Ws 16KB + Xt 16KB = 32KB -> 3 blocks/CU (782 blocks ~ all resident).
template<int IN_BF16>
__global__ __launch_bounds__(256, 3) void k_gemm(const void* __restrict__ Xv, const float* __restrict__ W,
    uint* __restrict__ Y, int nrows){
  __shared__ float Ws[32*128];   // [k_local][col]
  __shared__ float Xt[32*128];   // [k_local][row], XOR-swizzled rows
  int t = threadIdx.x;
  int row0 = blockIdx.x * 128;
  int tc = t & 15, tr = t >> 4;
  float acc[8][8];
  #pragma unroll
  for (int i=0;i<8;i++)
    #pragma unroll
    for (int j=0;j<8;j++) acc[i][j]=0.f;

  for (int ph = 0; ph < 4; ++ph){
    #pragma unroll
    for (int it = 0; it < 4; ++it){
      int f = it*256 + t;
      ((float4*)Ws)[f] = ((const float4*)W)[ph*1024 + f];
    }
    if (!IN_BF16){
      const float* X = (const float*)Xv;
      #pragma unroll
      for (int it = 0; it < 4; ++it){
        int f = it*256 + t;                  // 0..1023
        int r  = f >> 3;                     // local row 0..127
        int c4 = f & 7;                      // float4 within k-quarter
        int gr = row0 + r;
        float4 v;
        if (gr < nrows) v = ((const float4*)X)[(size_t)gr*32 + ph*8 + c4];
        else            v = make_float4(0.f,0.f,0.f,0.f);
        int swz = (c4 & 3) << 3;             // ((k>>2)&3)<<3 for k=4*c4+j
        int rp  = r ^ swz;
        Xt[(c4*4+0)*128 + rp] = v.x;
        Xt[(c4*4+1)*128 + rp] = v.y;
        Xt[(c4*4+2)*128 + rp] = v.z;
        Xt[(c4*4+3)*128 + rp] = v.w;
      }
    } else {
      const uint* X = (const uint*)Xv;       // 64 uints (128 bf16) per row
      #pragma unroll
      for (int it = 0; it < 2; ++it){
        int f = it*256 + t;                  // 0..511
        int r  = f >> 2;                     // local row 0..127
        int c8 = f & 3;                      // uint4 (8 bf16) within k-quarter
        int gr = row0 + r;
        uint4 u;
        if (gr < nrows) u = ((const uint4*)X)[(size_t)gr*16 + ph*4 + c8];
        else            u = make_uint4(0,0,0,0);
        int kb = c8*8;
        int swzA = ((c8*2  ) & 3) << 3;
        int swzB = ((c8*2+1) & 3) << 3;
        int rpA = r ^ swzA, rpB = r ^ swzB;
        Xt[(kb+0)*128 + rpA] = __uint_as_float(u.x << 16);
        Xt[(kb+1)*128 + rpA] = __uint_as_float(u.x & 0xFFFF0000u);
        Xt[(kb+2)*128 + rpA] = __uint_as_float(u.y << 16);
        Xt[(kb+3)*128 + rpA] = __uint_as_float(u.y & 0xFFFF0000u);
        Xt[(kb+4)*128 + rpB] = __uint_as_float(u.z << 16);
        Xt[(kb+5)*128 + rpB] = __uint_as_float(u.z & 0xFFFF0000u);
        Xt[(kb+6)*128 + rpB] = __uint_as_float(u.w << 16);
        Xt[(kb+7)*128 + rpB] = __uint_as_float(u.w & 0xFFFF0000u);
      }
    }
    __syncthreads();
    #pragma unroll 4
    for (int kl = 0; kl < 32; ++kl){
      int swz = ((kl >> 2) & 3) << 3;
      int xb  = kl*128 + ((tr*8) ^ swz);
      float4 xa = *(const float4*)&Xt[xb];
      float4 xc = *(const float4*)&Xt[xb + 4];
      float4 wa = *(const float4*)&Ws[kl*128 + tc*8];
      float4 wb = *(const float4*)&Ws[kl*128 + tc*8 + 4];
      float xr[8] = {xa.x,xa.y,xa.z,xa.w,xc.x,xc.y,xc.z,xc.w};
      float wr[8] = {wa.x,wa.y,wa.z,wa.w,wb.x,wb.y,wb.z,wb.w};
      #pragma unroll
      for (int i=0;i<8;i++)
        #pragma unroll
        for (int j=0;j<8;j++)
          acc[i][j] = fmaf(xr[i], wr[j], acc[i][j]);
    }
    __syncthreads();
  }
  #pragma unroll
  for (int i=0;i<8;i++){
    int r = row0 + tr*8 + i;
    if (r < nrows){
      uint4 o;
      o.x = pk2(acc[i][0], acc[i][1]);
      o.y = pk2(acc[i][2], acc[i][3]);
      o.z = pk2(acc[i][4], acc[i][5]);
      o.w = pk2(acc[i][6], acc[i][7]);
      ((uint4*)Y)[(size_t)r*16 + tc] = o;
    }
  }
}

// ---------------- CSR aggregation + bias + ELU ----------------
// one WAVE per node (4 nodes / 256-thread block); lane = bf16 channel pair;
// 16x edge unroll -> 16 gathers in flight per wave.
template<int OUT_BF16>
__global__ __launch_bounds__(256) void k_agg(const uint* __restrict__ H,
    const int* __restrict__ rowptr, const int* __restrict__ deg,
    const uint* __restrict__ es, const float* __restrict__ bias,
    void* __restrict__ outv){
  int wid  = threadIdx.x >> 6;
  int lane = threadIdx.x & 63;
  int n = blockIdx.x*4 + wid;            // grid*4 == NN exactly
  int e0 = rowptr[n];
  int e1 = e0 + deg[n] + 1;
  float a0 = 0.f, a1 = 0.f, a2 = 0.f, a3 = 0.f;
  int e = e0;

#define ASTEP(k,A,B) { uint p##k = es[e+k]; \
    uint h##k = H[(size_t)(p##k & 0x1FFFFu)*64 + lane]; \
    float w##k = __uint_as_float((p##k >> 17) << 16); \
    A = fmaf(w##k, __uint_as_float(h##k << 16), A); \
    B = fmaf(w##k, __uint_as_float(h##k & 0xFFFF0000u), B); }

  for (; e + 16 <= e1; e += 16){
    ASTEP( 0,a0,a1) ASTEP( 1,a2,a3) ASTEP( 2,a0,a1) ASTEP( 3,a2,a3)
    ASTEP( 4,a0,a1) ASTEP( 5,a2,a3) ASTEP( 6,a0,a1) ASTEP( 7,a2,a3)
    ASTEP( 8,a0,a1) ASTEP( 9,a2,a3) ASTEP(10,a0,a1) ASTEP(11,a2,a3)
    ASTEP(12,a0,a1) ASTEP(13,a2,a3) ASTEP(14,a0,a1) ASTEP(15,a2,a3)
  }
  for (; e + 4 <= e1; e += 4){
    ASTEP(0,a0,a1) ASTEP(1,a2,a3) ASTEP(2,a0,a1) ASTEP(3,a2,a3)
  }
  for (; e < e1; ++e){
    ASTEP(0,a0,a1)
  }
#undef ASTEP

  float2 b = *(const float2*)&bias[lane*2];
  float v0 = a0 + a2 + b.x, v1 = a1 + a3 + b.y;
  v0 = (v0 > 0.f) ? v0 : expm1f(v0);
  v1 = (v1 > 0.f) ? v1 : expm1f(v1);
  if (OUT_BF16){
    ((uint*)outv)[(size_t)n*64 + lane] = pk2(v0, v1);
  } else {
    float2 o; o.x = v0; o.y = v1;
    *(float2*)&((float*)outv)[(size_t)n*DD + lane*2] = o;
  }
}

// ---------------- launch ----------------

extern "C" void kernel_launch(void* const* d_in, const int* in_sizes, int n_in,
                              void* d_out, int out_size, void* d_ws, size_t ws_size,
                              hipStream_t stream){
  const float* x  = (const float*)d_in[0];
  const int*   ei = (const int*)d_in[1];   // [2, NE]: src row then dst row
  const float* W1 = (const float*)d_in[2];
  const float* b1 = (const float*)d_in[3];
  const float* W2 = (const float*)d_in[4];
  const float* b2 = (const float*)d_in[5];

  // workspace carve-up (int units), ~46.9 MB:
  //   bedge (12.3MB, dead after k_build) aliases H (written first by k_gemm<0>)
  int*   ws_i   = (int*)d_ws;
  int*   bcnt   = ws_i + 0;                 // 500*8*16 = 64000 (64B-padded sub-counters)
  int*   deg    = ws_i + 64000;             // 100000
  float* dis    = (float*)(ws_i + 164000);  // 100000
  int*   rowptr = ws_i + 264000;            // 100000
  uint*  es     = (uint*)(ws_i + 364000);   // 1700000
  uint*  H      = (uint*)(ws_i + 2064000);  // 6400000 bf16x2 (byte 8256000, 16B-aligned)
  uint*  bedge  = H;                        // alias: 500*6144 = 3072000 uints
  uint*  out1   = (uint*)(ws_i + 8464000);  // 3200000 bf16x2

  hipMemsetAsync(bcnt, 0, 64000*sizeof(int), stream);

  k_bucket<<<6250, 256, 0, stream>>>(ei, bcnt, bedge);
  k_deg   <<<NB,   256, 0, stream>>>(bcnt, bedge, deg, dis);
  k_build <<<NB,   256, 0, stream>>>(bcnt, bedge, dis, rowptr, es);

  // layer 1: H = bf16(x@W1) ; out1 = bf16(elu(agg(H) + b1))
  k_gemm<0><<<782,   256, 0, stream>>>(x, W1, H, NN);
  k_agg<1> <<<25000, 256, 0, stream>>>(H, rowptr, deg, es, b1, out1);
  // layer 2: H = bf16(out1@W2) ; out = elu(agg(H) + b2)
  k_gemm<1><<<782,   256, 0, stream>>>(out1, W2, H, NN);
  k_agg<0> <<<25000, 256, 0, stream>>>(H, rowptr, deg, es, b2, d_out);
}

// Round 7
// 338.761 us; speedup vs baseline: 1.0181x; 1.0181x over previous
//
#include <hip/hip_runtime.h>
#include <math.h>

#define NN 100000
#define NE 1600000
#define NT (NE + NN)   // 1700000 edges incl. self-loops
#define DD 128
#define NB 500          // dst buckets
#define BR 200          // node range per bucket (NB*BR == NN)
#define BCAP 4096       // bucket capacity (mean 3200, sigma 56 -> 15.9 sigma headroom)
#define NCH 4096        // edges per k_bucket block
#define NBK 391         // ceil(NE/NCH)
#define BMAGIC 21474837u // ceil(2^32/200); exact for d < 100000

typedef unsigned int uint;
typedef unsigned short ushort;

// round-to-nearest-even fp32 -> bf16 (16-bit payload in a uint)
__device__ __forceinline__ uint bfr(float f){
  uint u = __float_as_uint(f);
  return (u + 0x7FFFu + ((u >> 16) & 1u)) >> 16;
}
__device__ __forceinline__ uint pk2(float a, float b){
  return (bfr(a) & 0xFFFFu) | (bfr(b) << 16);
}

// ---------------- preprocessing: 2-phase LDS-histogram bucket sort ----------------

// 4096 edges/block. Phase A: pack entries + LDS histogram over 500 buckets.
// Phase B: ONE global atomic per (block,bucket) reserves a contiguous range,
// then edges scatter into it (fill offsets via LDS atomics).
__global__ __launch_bounds__(256) void k_bucket(const int* __restrict__ ei,
    int* __restrict__ gcnt, uint* __restrict__ bedge){
  __shared__ uint   ent[NCH];    // src(17b) | d_local(8b)<<17
  __shared__ ushort bbs[NCH];    // bucket id
  __shared__ int    hist[NB];
  __shared__ int    fl[NB];
  __shared__ int    gb[NB];
  int t = threadIdx.x;
  int base = blockIdx.x * NCH;
  int nv = NE - base; if (nv > NCH) nv = NCH;
  for (int b = t; b < NB; b += 256){ hist[b] = 0; fl[b] = 0; }
  __syncthreads();
  for (int j = t; j < nv; j += 256){
    int i = base + j;                      // coalesced
    uint s = (uint)ei[i];
    uint d = (uint)ei[NE + i];
    uint b = __umulhi(d, BMAGIC);          // d / 200
    uint dl = d - b*BR;
    ent[j] = s | (dl << 17);
    bbs[j] = (ushort)b;
    atomicAdd(&hist[b], 1);
  }
  __syncthreads();
  for (int b = t; b < NB; b += 256){
    int h = hist[b];
    gb[b] = h ? atomicAdd(&gcnt[b*16], h) : 0;   // bulk reservation
  }
  __syncthreads();
  for (int j = t; j < nv; j += 256){
    uint b = bbs[j];
    int q = atomicAdd(&fl[b], 1);          // LDS fill
    bedge[(size_t)b*BCAP + gb[b] + q] = ent[j];
  }
}

// single-block exclusive scan of bucket totals (incl. +BR self-loops each)
__global__ __launch_bounds__(512) void k_bscan(const int* __restrict__ gcnt, int* __restrict__ bbase){
  __shared__ int s[512];
  int t = threadIdx.x;
  int v = (t < NB) ? (gcnt[t*16] + BR) : 0;
  s[t] = v;
  __syncthreads();
  for (int off = 1; off < 512; off <<= 1){
    int a = (t >= off) ? s[t-off] : 0;
    __syncthreads();
    s[t] += a;
    __syncthreads();
  }
  if (t < NB) bbase[t] = s[t] - v;
}

// per-bucket LDS degree count -> coalesced deg/dis writes
__global__ __launch_bounds__(256) void k_deg(const int* __restrict__ gcnt,
    const uint* __restrict__ bedge, int* __restrict__ deg, float* __restrict__ dis){
  __shared__ int cl[BR];
  int b = blockIdx.x, t = threadIdx.x;
  if (t < BR) cl[t] = 0;
  __syncthreads();
  int cnt = gcnt[b*16];
  for (int e = t; e < cnt; e += 256){
    atomicAdd(&cl[bedge[(size_t)b*BCAP + e] >> 17], 1);
  }
  __syncthreads();
  if (t < BR){
    int n = b*BR + t;
    int dg = cl[t];
    deg[n] = dg;                           // in-degree excl self-loop
    dis[n] = rsqrtf((float)(dg + 1));
  }
}

// per-bucket CSR build: LDS count + scan, norms, contiguous es/rowptr writes
__global__ __launch_bounds__(256) void k_build(const int* __restrict__ gcnt,
    const int* __restrict__ bbase, const uint* __restrict__ bedge,
    const float* __restrict__ dis, int* __restrict__ rowptr, uint* __restrict__ es){
  __shared__ uint  eL[BCAP];
  __shared__ int   cl[BR];
  __shared__ int   fl[BR];
  __shared__ float dl_[BR];
  __shared__ int   pf[256];
  int b = blockIdx.x, t = threadIdx.x;
  int base = bbase[b];
  if (t < BR){ cl[t] = 0; fl[t] = 0; }
  __syncthreads();
  int cnt = gcnt[b*16];
  for (int e = t; e < cnt; e += 256){
    uint u = bedge[(size_t)b*BCAP + e];
    eL[e] = u;
    atomicAdd(&cl[u >> 17], 1);
  }
  __syncthreads();
  // inclusive scan over (cl[i]+1)
  int v = (t < BR) ? (cl[t] + 1) : 0;
  pf[t] = v;
  __syncthreads();
  for (int off = 1; off < 256; off <<= 1){
    int a = (t >= off) ? pf[t-off] : 0;
    __syncthreads();
    pf[t] += a;
    __syncthreads();
  }
  if (t < BR){
    int n  = b*BR + t;
    int p0 = base + pf[t] - v;             // exclusive prefix
    rowptr[n] = p0;
    float dn = dis[n];
    dl_[t] = dn;
    es[p0 + cl[t]] = (uint)n | ((bfr(dn*dn) & 0x7FFFu) << 17);  // self-loop last
  }
  __syncthreads();
  for (int e = t; e < cnt; e += 256){
    uint u = eL[e];
    uint s = u & 0x1FFFFu;
    int  dloc = u >> 17;
    int  q  = atomicAdd(&fl[dloc], 1);
    int  p0 = base + pf[dloc] - (cl[dloc] + 1);
    es[p0 + q] = s | ((bfr(dis[s] * dl_[dloc]) & 0x7FFFu) << 17);
  }
}

// ---------------- GEMM -> bf16: Y[nrows,128](bf16) = X[nrows,128] @ W[128,128] ----------------
// 128 rows/block, 256 threads, 8x8 register tile/thread, quarter-K phases.
// LDS: Ws 16KB + Xt 16KB = 32KB -> 3 blocks/CU (782 blocks ~ all resident).
template<int IN_BF16>
__global__ __launch_bounds__(256, 3) void k_gemm(const void* __restrict__ Xv, const float* __restrict__ W,
    uint* __restrict__ Y, int nrows){
  __shared__ float Ws[32*128];   // [k_local][col]
  __shared__ float Xt[32*128];   // [k_local][row], XOR-swizzled rows
  int t = threadIdx.x;
  int row0 = blockIdx.x * 128;
  int tc = t & 15, tr = t >> 4;
  float acc[8][8];
  #pragma unroll
  for (int i=0;i<8;i++)
    #pragma unroll
    for (int j=0;j<8;j++) acc[i][j]=0.f;

  for (int ph = 0; ph < 4; ++ph){
    #pragma unroll
    for (int it = 0; it < 4; ++it){
      int f = it*256 + t;
      ((float4*)Ws)[f] = ((const float4*)W)[ph*1024 + f];
    }
    if (!IN_BF16){
      const float* X = (const float*)Xv;
      #pragma unroll
      for (int it = 0; it < 4; ++it){
        int f = it*256 + t;                  // 0..1023
        int r  = f >> 3;                     // local row 0..127
        int c4 = f & 7;                      // float4 within k-quarter
        int gr = row0 + r;
        float4 v;
        if (gr < nrows) v = ((const float4*)X)[(size_t)gr*32 + ph*8 + c4];
        else            v = make_float4(0.f,0.f,0.f,0.f);
        int swz = (c4 & 3) << 3;             // ((k>>2)&3)<<3 for k=4*c4+j
        int rp  = r ^ swz;
        Xt[(c4*4+0)*128 + rp] = v.x;
        Xt[(c4*4+1)*128 + rp] = v.y;
        Xt[(c4*4+2)*128 + rp] = v.z;
        Xt[(c4*4+3)*128 + rp] = v.w;
      }
    } else {
      const uint* X = (const uint*)Xv;       // 64 uints (128 bf16) per row
      #pragma unroll
      for (int it = 0; it < 2; ++it){
        int f = it*256 + t;                  // 0..511
        int r  = f >> 2;                     // local row 0..127
        int c8 = f & 3;                      // uint4 (8 bf16) within k-quarter
        int gr = row0 + r;
        uint4 u;
        if (gr < nrows) u = ((const uint4*)X)[(size_t)gr*16 + ph*4 + c8];
        else            u = make_uint4(0,0,0,0);
        int kb = c8*8;
        int swzA = ((c8*2  ) & 3) << 3;
        int swzB = ((c8*2+1) & 3) << 3;
        int rpA = r ^ swzA, rpB = r ^ swzB;
        Xt[(kb+0)*128 + rpA] = __uint_as_float(u.x << 16);
        Xt[(kb+1)*128 + rpA] = __uint_as_float(u.x & 0xFFFF0000u);
        Xt[(kb+2)*128 + rpA] = __uint_as_float(u.y << 16);
        Xt[(kb+3)*128 + rpA] = __uint_as_float(u.y & 0xFFFF0000u);
        Xt[(kb+4)*128 + rpB] = __uint_as_float(u.z << 16);
        Xt[(kb+5)*128 + rpB] = __uint_as_float(u.z & 0xFFFF0000u);
        Xt[(kb+6)*128 + rpB] = __uint_as_float(u.w << 16);
        Xt[(kb+7)*128 + rpB] = __uint_as_float(u.w & 0xFFFF0000u);
      }
    }
    __syncthreads();
    #pragma unroll 4
    for (int kl = 0; kl < 32; ++kl){
      int swz = ((kl >> 2) & 3) << 3;
      int xb  = kl*128 + ((tr*8) ^ swz);
      float4 xa = *(const float4*)&Xt[xb];
      float4 xc = *(const float4*)&Xt[xb + 4];
      float4 wa = *(const float4*)&Ws[kl*128 + tc*8];
      float4 wb = *(const float4*)&Ws[kl*128 + tc*8 + 4];
      float xr[8] = {xa.x,xa.y,xa.z,xa.w,xc.x,xc.y,xc.z,xc.w};
      float wr[8] = {wa.x,wa.y,wa.z,wa.w,wb.x,wb.y,wb.z,wb.w};
      #pragma unroll
      for (int i=0;i<8;i++)
        #pragma unroll
        for (int j=0;j<8;j++)
          acc[i][j] = fmaf(xr[i], wr[j], acc[i][j]);
    }
    __syncthreads();
  }
  #pragma unroll
  for (int i=0;i<8;i++){
    int r = row0 + tr*8 + i;
    if (r < nrows){
      uint4 o;
      o.x = pk2(acc[i][0], acc[i][1]);
      o.y = pk2(acc[i][2], acc[i][3]);
      o.z = pk2(acc[i][4], acc[i][5]);
      o.w = pk2(acc[i][6], acc[i][7]);
      ((uint4*)Y)[(size_t)r*16 + tc] = o;
    }
  }
}

// ---------------- CSR aggregation + bias + ELU ----------------
// one WAVE per node (4 nodes / 256-thread block); lane = bf16 channel pair;
// 16x edge unroll -> 16 gathers in flight per wave.
template<int OUT_BF16>
__global__ __launch_bounds__(256) void k_agg(const uint* __restrict__ H,
    const int* __restrict__ rowptr, const int* __restrict__ deg,
    const uint* __restrict__ es, const float* __restrict__ bias,
    void* __restrict__ outv){
  int wid  = threadIdx.x >> 6;
  int lane = threadIdx.x & 63;
  int n = blockIdx.x*4 + wid;            // grid*4 == NN exactly
  int e0 = rowptr[n];
  int e1 = e0 + deg[n] + 1;
  float a0 = 0.f, a1 = 0.f, a2 = 0.f, a3 = 0.f;
  int e = e0;

#define ASTEP(k,A,B) { uint p##k = es[e+k]; \
    uint h##k = H[(size_t)(p##k & 0x1FFFFu)*64 + lane]; \
    float w##k = __uint_as_float((p##k >> 17) << 16); \
    A = fmaf(w##k, __uint_as_float(h##k << 16), A); \
    B = fmaf(w##k, __uint_as_float(h##k & 0xFFFF0000u), B); }

  for (; e + 16 <= e1; e += 16){
    ASTEP( 0,a0,a1) ASTEP( 1,a2,a3) ASTEP( 2,a0,a1) ASTEP( 3,a2,a3)
    ASTEP( 4,a0,a1) ASTEP( 5,a2,a3) ASTEP( 6,a0,a1) ASTEP( 7,a2,a3)
    ASTEP( 8,a0,a1) ASTEP( 9,a2,a3) ASTEP(10,a0,a1) ASTEP(11,a2,a3)
    ASTEP(12,a0,a1) ASTEP(13,a2,a3) ASTEP(14,a0,a1) ASTEP(15,a2,a3)
  }
  for (; e + 4 <= e1; e += 4){
    ASTEP(0,a0,a1) ASTEP(1,a2,a3) ASTEP(2,a0,a1) ASTEP(3,a2,a3)
  }
  for (; e < e1; ++e){
    ASTEP(0,a0,a1)
  }
#undef ASTEP

  float2 b = *(const float2*)&bias[lane*2];
  float v0 = a0 + a2 + b.x, v1 = a1 + a3 + b.y;
  v0 = (v0 > 0.f) ? v0 : expm1f(v0);
  v1 = (v1 > 0.f) ? v1 : expm1f(v1);
  if (OUT_BF16){
    ((uint*)outv)[(size_t)n*64 + lane] = pk2(v0, v1);
  } else {
    float2 o; o.x = v0; o.y = v1;
    *(float2*)&((float*)outv)[(size_t)n*DD + lane*2] = o;
  }
}

// ---------------- launch ----------------

extern "C" void kernel_launch(void* const* d_in, const int* in_sizes, int n_in,
                              void* d_out, int out_size, void* d_ws, size_t ws_size,
                              hipStream_t stream){
  const float* x  = (const float*)d_in[0];
  const int*   ei = (const int*)d_in[1];   // [2, NE]: src row then dst row
  const float* W1 = (const float*)d_in[2];
  const float* b1 = (const float*)d_in[3];
  const float* W2 = (const float*)d_in[4];
  const float* b2 = (const float*)d_in[5];

  // workspace carve-up (int units), ~46.7 MB:
  //   bedge (8.2MB, dead after k_build) aliases H (written first by k_gemm<0>)
  int*   ws_i   = (int*)d_ws;
  int*   gcnt   = ws_i + 0;                 // 500*16 = 8000 (64B-padded counters)
  int*   bbase  = ws_i + 8000;              // 500
  int*   deg    = ws_i + 8500;              // 100000
  float* dis    = (float*)(ws_i + 108500);  // 100000
  int*   rowptr = ws_i + 208500;            // 100000
  uint*  es     = (uint*)(ws_i + 308500);   // 1700000
  uint*  H      = (uint*)(ws_i + 2008500);  // 6400000 bf16x2 (byte 8034000, 16B-aligned)
  uint*  bedge  = H;                        // alias: 500*4096 = 2048000 uints
  uint*  out1   = (uint*)(ws_i + 8408500);  // 3200000 bf16x2

  hipMemsetAsync(gcnt, 0, 8000*sizeof(int), stream);

  k_bucket<<<NBK, 256, 0, stream>>>(ei, gcnt, bedge);
  k_bscan <<<1,   512, 0, stream>>>(gcnt, bbase);
  k_deg   <<<NB,  256, 0, stream>>>(gcnt, bedge, deg, dis);
  k_build <<<NB,  256, 0, stream>>>(gcnt, bbase, bedge, dis, rowptr, es);

  // layer 1: H = bf16(x@W1) ; out1 = bf16(elu(agg(H) + b1))
  k_gemm<0><<<782,   256, 0, stream>>>(x, W1, H, NN);
  k_agg<1> <<<25000, 256, 0, stream>>>(H, rowptr, deg, es, b1, out1);
  // layer 2: H = bf16(out1@W2) ; out = elu(agg(H) + b2)
  k_gemm<1><<<782,   256, 0, stream>>>(out1, W2, H, NN);
  k_agg<0> <<<25000, 256, 0, stream>>>(H, rowptr, deg, es, b2, d_out);
}

// Round 8
// 312.003 us; speedup vs baseline: 1.1054x; 1.0858x over previous
//
#include <hip/hip_runtime.h>
#include <math.h>

#define NN 100000
#define NE 1600000
#define NT (NE + NN)   // 1700000 edges incl. self-loops
#define DD 128
#define NB 500          // dst buckets
#define BR 200          // node range per bucket (NB*BR == NN)
#define BCAP 4096       // bucket capacity (mean 3200, sigma 56 -> 15.9 sigma headroom)
#define NCH 2048        // edges per k_bucket block
#define NBK 782         // ceil(NE/NCH)
#define BMAGIC 21474837u // ceil(2^32/200); exact for d < 100000

typedef unsigned int uint;
typedef unsigned short ushort;

// round-to-nearest-even fp32 -> bf16 (16-bit payload in a uint)
__device__ __forceinline__ uint bfr(float f){
  uint u = __float_as_uint(f);
  return (u + 0x7FFFu + ((u >> 16) & 1u)) >> 16;
}
__device__ __forceinline__ uint pk2(float a, float b){
  return (bfr(a) & 0xFFFFu) | (bfr(b) << 16);
}

// ---------------- preprocessing: 2-phase LDS-histogram bucket sort ----------------

// 2048 edges/block. Phase A: pack entries + LDS histogram over 500 buckets.
// Phase B: ONE global atomic per (block,bucket) reserves a contiguous range,
// then edges scatter into it (fill offsets via LDS atomics).
__global__ __launch_bounds__(256) void k_bucket(const int* __restrict__ ei,
    int* __restrict__ gcnt, uint* __restrict__ bedge){
  __shared__ uint   ent[NCH];    // src(17b) | d_local(8b)<<17
  __shared__ ushort bbs[NCH];    // bucket id
  __shared__ int    hist[NB];
  __shared__ int    fl[NB];
  __shared__ int    gb[NB];
  int t = threadIdx.x;
  int base = blockIdx.x * NCH;
  int nv = NE - base; if (nv > NCH) nv = NCH;
  for (int b = t; b < NB; b += 256){ hist[b] = 0; fl[b] = 0; }
  __syncthreads();
  for (int j = t; j < nv; j += 256){
    int i = base + j;                      // coalesced
    uint s = (uint)ei[i];
    uint d = (uint)ei[NE + i];
    uint b = __umulhi(d, BMAGIC);          // d / 200
    uint dl = d - b*BR;
    ent[j] = s | (dl << 17);
    bbs[j] = (ushort)b;
    atomicAdd(&hist[b], 1);
  }
  __syncthreads();
  for (int b = t; b < NB; b += 256){
    int h = hist[b];
    gb[b] = h ? atomicAdd(&gcnt[b*16], h) : 0;   // bulk reservation
  }
  __syncthreads();
  for (int j = t; j < nv; j += 256){
    uint b = bbs[j];
    int q = atomicAdd(&fl[b], 1);          // LDS fill
    bedge[(size_t)b*BCAP + gb[b] + q] = ent[j];
  }
}

// single-block exclusive scan of bucket totals (incl. +BR self-loops each)
__global__ __launch_bounds__(512) void k_bscan(const int* __restrict__ gcnt, int* __restrict__ bbase){
  __shared__ int s[512];
  int t = threadIdx.x;
  int v = (t < NB) ? (gcnt[t*16] + BR) : 0;
  s[t] = v;
  __syncthreads();
  for (int off = 1; off < 512; off <<= 1){
    int a = (t >= off) ? s[t-off] : 0;
    __syncthreads();
    s[t] += a;
    __syncthreads();
  }
  if (t < NB) bbase[t] = s[t] - v;
}

// fused per-bucket CSR build: LDS count + scan -> deg/dis/rowptr/es (es = plain src)
__global__ __launch_bounds__(256) void k_build(const int* __restrict__ gcnt,
    const int* __restrict__ bbase, const uint* __restrict__ bedge,
    float* __restrict__ dis, int* __restrict__ rowptr, uint* __restrict__ es){
  __shared__ uint eL[BCAP];
  __shared__ int  cl[BR];
  __shared__ int  fl[BR];
  __shared__ int  pf[256];
  int b = blockIdx.x, t = threadIdx.x;
  int base = bbase[b];
  if (t < BR){ cl[t] = 0; fl[t] = 0; }
  __syncthreads();
  int cnt = gcnt[b*16];
  for (int e = t; e < cnt; e += 256){
    uint u = bedge[(size_t)b*BCAP + e];
    eL[e] = u;
    atomicAdd(&cl[u >> 17], 1);
  }
  __syncthreads();
  // inclusive scan over (cl[i]+1)
  int v = (t < BR) ? (cl[t] + 1) : 0;
  pf[t] = v;
  __syncthreads();
  for (int off = 1; off < 256; off <<= 1){
    int a = (t >= off) ? pf[t-off] : 0;
    __syncthreads();
    pf[t] += a;
    __syncthreads();
  }
  if (t < BR){
    int n  = b*BR + t;
    int p0 = base + pf[t] - v;             // exclusive prefix (globally monotone)
    rowptr[n] = p0;
    dis[n] = rsqrtf((float)(cl[t] + 1));
    es[p0 + cl[t]] = (uint)n;              // self-loop last
  }
  if (b == NB-1 && t == 0) rowptr[NN] = NT;
  __syncthreads();
  for (int e = t; e < cnt; e += 256){
    uint u = eL[e];
    int  dloc = u >> 17;
    int  q  = atomicAdd(&fl[dloc], 1);
    int  p0 = base + pf[dloc] - (cl[dloc] + 1);
    es[p0 + q] = u & 0x1FFFFu;
  }
}

// ---------------- GEMM -> dis-scaled bf16: Y[r] = bf16(dis[r] * (X@W)[r]) ----------------
// 128 rows/block, 256 threads, 8x8 register tile/thread, quarter-K phases.
// LDS: Ws 16KB + Xt 16KB = 32KB -> 3 blocks/CU (782 blocks ~ all resident).
template<int IN_BF16>
__global__ __launch_bounds__(256, 3) void k_gemm(const void* __restrict__ Xv, const float* __restrict__ W,
    const float* __restrict__ dis, uint* __restrict__ Y, int nrows){
  __shared__ float Ws[32*128];   // [k_local][col]
  __shared__ float Xt[32*128];   // [k_local][row], XOR-swizzled rows
  int t = threadIdx.x;
  int row0 = blockIdx.x * 128;
  int tc = t & 15, tr = t >> 4;
  float acc[8][8];
  #pragma unroll
  for (int i=0;i<8;i++)
    #pragma unroll
    for (int j=0;j<8;j++) acc[i][j]=0.f;

  for (int ph = 0; ph < 4; ++ph){
    #pragma unroll
    for (int it = 0; it < 4; ++it){
      int f = it*256 + t;
      ((float4*)Ws)[f] = ((const float4*)W)[ph*1024 + f];
    }
    if (!IN_BF16){
      const float* X = (const float*)Xv;
      #pragma unroll
      for (int it = 0; it < 4; ++it){
        int f = it*256 + t;                  // 0..1023
        int r  = f >> 3;                     // local row 0..127
        int c4 = f & 7;                      // float4 within k-quarter
        int gr = row0 + r;
        float4 v;
        if (gr < nrows) v = ((const float4*)X)[(size_t)gr*32 + ph*8 + c4];
        else            v = make_float4(0.f,0.f,0.f,0.f);
        int swz = (c4 & 3) << 3;             // ((k>>2)&3)<<3 for k=4*c4+j
        int rp  = r ^ swz;
        Xt[(c4*4+0)*128 + rp] = v.x;
        Xt[(c4*4+1)*128 + rp] = v.y;
        Xt[(c4*4+2)*128 + rp] = v.z;
        Xt[(c4*4+3)*128 + rp] = v.w;
      }
    } else {
      const uint* X = (const uint*)Xv;       // 64 uints (128 bf16) per row
      #pragma unroll
      for (int it = 0; it < 2; ++it){
        int f = it*256 + t;                  // 0..511
        int r  = f >> 2;                     // local row 0..127
        int c8 = f & 3;                      // uint4 (8 bf16) within k-quarter
        int gr = row0 + r;
        uint4 u;
        if (gr < nrows) u = ((const uint4*)X)[(size_t)gr*16 + ph*4 + c8];
        else            u = make_uint4(0,0,0,0);
        int kb = c8*8;
        int swzA = ((c8*2  ) & 3) << 3;
        int swzB = ((c8*2+1) & 3) << 3;
        int rpA = r ^ swzA, rpB = r ^ swzB;
        Xt[(kb+0)*128 + rpA] = __uint_as_float(u.x << 16);
        Xt[(kb+1)*128 + rpA] = __uint_as_float(u.x & 0xFFFF0000u);
        Xt[(kb+2)*128 + rpA] = __uint_as_float(u.y << 16);
        Xt[(kb+3)*128 + rpA] = __uint_as_float(u.y & 0xFFFF0000u);
        Xt[(kb+4)*128 + rpB] = __uint_as_float(u.z << 16);
        Xt[(kb+5)*128 + rpB] = __uint_as_float(u.z & 0xFFFF0000u);
        Xt[(kb+6)*128 + rpB] = __uint_as_float(u.w << 16);
        Xt[(kb+7)*128 + rpB] = __uint_as_float(u.w & 0xFFFF0000u);
      }
    }
    __syncthreads();
    #pragma unroll 4
    for (int kl = 0; kl < 32; ++kl){
      int swz = ((kl >> 2) & 3) << 3;
      int xb  = kl*128 + ((tr*8) ^ swz);
      float4 xa = *(const float4*)&Xt[xb];
      float4 xc = *(const float4*)&Xt[xb + 4];
      float4 wa = *(const float4*)&Ws[kl*128 + tc*8];
      float4 wb = *(const float4*)&Ws[kl*128 + tc*8 + 4];
      float xr[8] = {xa.x,xa.y,xa.z,xa.w,xc.x,xc.y,xc.z,xc.w};
      float wr[8] = {wa.x,wa.y,wa.z,wa.w,wb.x,wb.y,wb.z,wb.w};
      #pragma unroll
      for (int i=0;i<8;i++)
        #pragma unroll
        for (int j=0;j<8;j++)
          acc[i][j] = fmaf(xr[i], wr[j], acc[i][j]);
    }
    __syncthreads();
  }
  #pragma unroll
  for (int i=0;i<8;i++){
    int r = row0 + tr*8 + i;
    if (r < nrows){
      float dr = dis[r];                     // premultiply dis[src] into H row
      uint4 o;
      o.x = pk2(acc[i][0]*dr, acc[i][1]*dr);
      o.y = pk2(acc[i][2]*dr, acc[i][3]*dr);
      o.z = pk2(acc[i][4]*dr, acc[i][5]*dr);
      o.w = pk2(acc[i][6]*dr, acc[i][7]*dr);
      ((uint4*)Y)[(size_t)r*16 + tc] = o;
    }
  }
}

// ---------------- CSR aggregation + bias + ELU ----------------
// out[n] = elu(dis[n] * sum_{s in N(n)} H'[s] + b); H' rows pre-scaled by dis[s].
// one WAVE per node (4 nodes / 256-thread block); lane = bf16 channel pair;
// 16x edge unroll -> 16 gathers in flight per wave.
template<int OUT_BF16>
__global__ __launch_bounds__(256) void k_agg(const uint* __restrict__ H,
    const int* __restrict__ rowptr, const float* __restrict__ dis,
    const uint* __restrict__ es, const float* __restrict__ bias,
    void* __restrict__ outv){
  int wid  = threadIdx.x >> 6;
  int lane = threadIdx.x & 63;
  int n = blockIdx.x*4 + wid;            // grid*4 == NN exactly
  int e0 = rowptr[n];
  int e1 = rowptr[n+1];
  float a0 = 0.f, a1 = 0.f, a2 = 0.f, a3 = 0.f;
  int e = e0;

#define ASTEP(k,A,B) { uint s##k = es[e+k]; \
    uint h##k = H[(size_t)s##k*64 + lane]; \
    A += __uint_as_float(h##k << 16); \
    B += __uint_as_float(h##k & 0xFFFF0000u); }

  for (; e + 16 <= e1; e += 16){
    ASTEP( 0,a0,a1) ASTEP( 1,a2,a3) ASTEP( 2,a0,a1) ASTEP( 3,a2,a3)
    ASTEP( 4,a0,a1) ASTEP( 5,a2,a3) ASTEP( 6,a0,a1) ASTEP( 7,a2,a3)
    ASTEP( 8,a0,a1) ASTEP( 9,a2,a3) ASTEP(10,a0,a1) ASTEP(11,a2,a3)
    ASTEP(12,a0,a1) ASTEP(13,a2,a3) ASTEP(14,a0,a1) ASTEP(15,a2,a3)
  }
  for (; e + 4 <= e1; e += 4){
    ASTEP(0,a0,a1) ASTEP(1,a2,a3) ASTEP(2,a0,a1) ASTEP(3,a2,a3)
  }
  for (; e < e1; ++e){
    ASTEP(0,a0,a1)
  }
#undef ASTEP

  float dn = dis[n];
  float2 b = *(const float2*)&bias[lane*2];
  float v0 = fmaf(dn, a0 + a2, b.x);
  float v1 = fmaf(dn, a1 + a3, b.y);
  v0 = (v0 > 0.f) ? v0 : expm1f(v0);
  v1 = (v1 > 0.f) ? v1 : expm1f(v1);
  if (OUT_BF16){
    ((uint*)outv)[(size_t)n*64 + lane] = pk2(v0, v1);
  } else {
    float2 o; o.x = v0; o.y = v1;
    *(float2*)&((float*)outv)[(size_t)n*DD + lane*2] = o;
  }
}

// ---------------- launch ----------------

extern "C" void kernel_launch(void* const* d_in, const int* in_sizes, int n_in,
                              void* d_out, int out_size, void* d_ws, size_t ws_size,
                              hipStream_t stream){
  const float* x  = (const float*)d_in[0];
  const int*   ei = (const int*)d_in[1];   // [2, NE]: src row then dst row
  const float* W1 = (const float*)d_in[2];
  const float* b1 = (const float*)d_in[3];
  const float* W2 = (const float*)d_in[4];
  const float* b2 = (const float*)d_in[5];

  // workspace carve-up (int units), every region 64-int (256B) aligned.
  // H's 256B alignment is CRITICAL: misaligned 256B rows straddle an extra
  // 128B line -> +42% gather FETCH (measured across R4..R7).
  // bedge (8.2MB, dead after k_build) aliases H (written first by k_gemm<0>).
  int*   ws_i   = (int*)d_ws;
  int*   gcnt   = ws_i + 0;                 // [0, 8000)  500*16 padded counters
  int*   bbase  = ws_i + 8000;              // [8000, 8576)  500 used
  float* dis    = (float*)(ws_i + 8576);    // [8576, 108608)  100000 used
  int*   rowptr = ws_i + 108608;            // [108608, 208704)  100001 used
  uint*  es     = (uint*)(ws_i + 208704);   // [208704, 1908736)  1700000 used
  uint*  H      = (uint*)(ws_i + 1908736);  // [1908736, 8308736)  byte 7634944 %256==0
  uint*  bedge  = H;                        // alias: 500*4096 = 2048000 uints
  uint*  out1   = (uint*)(ws_i + 8308736);  // [8308736, 11508736)  byte %256==0
  // total 11508736 ints = 46.03 MB

  hipMemsetAsync(gcnt, 0, 8000*sizeof(int), stream);

  k_bucket<<<NBK, 256, 0, stream>>>(ei, gcnt, bedge);
  k_bscan <<<1,   512, 0, stream>>>(gcnt, bbase);
  k_build <<<NB,  256, 0, stream>>>(gcnt, bbase, bedge, dis, rowptr, es);

  // layer 1: H = bf16(dis*(x@W1)) ; out1 = bf16(elu(dis*agg + b1))
  k_gemm<0><<<782,   256, 0, stream>>>(x, W1, dis, H, NN);
  k_agg<1> <<<25000, 256, 0, stream>>>(H, rowptr, dis, es, b1, out1);
  // layer 2: H = bf16(dis*(out1@W2)) ; out = elu(dis*agg + b2)
  k_gemm<1><<<782,   256, 0, stream>>>(out1, W2, dis, H, NN);
  k_agg<0> <<<25000, 256, 0, stream>>>(H, rowptr, dis, es, b2, d_out);
}

// Round 9
// 280.742 us; speedup vs baseline: 1.2285x; 1.1114x over previous
//
#include <hip/hip_runtime.h>
#include <math.h>

#define NN 100000
#define NE 1600000
#define NT (NE + NN)   // 1700000 edges incl. self-loops
#define DD 128
#define NB 500          // dst buckets
#define BR 200          // node range per bucket (NB*BR == NN)
#define BCAP 4096       // bucket capacity (mean 3200, sigma 56 -> 15.9 sigma headroom)
#define NCH 2048        // edges per k_bucket block
#define NBK 782         // ceil(NE/NCH)
#define NBG 1563        // ceil(NN/64) gemm blocks
#define BMAGIC 21474837u // ceil(2^32/200); exact for d < 100000

typedef unsigned int uint;
typedef unsigned short ushort;
typedef __attribute__((ext_vector_type(8))) short bf16x8;
typedef __attribute__((ext_vector_type(4))) float f32x4;

// round-to-nearest-even fp32 -> bf16 (16-bit payload in a uint)
__device__ __forceinline__ uint bfr(float f){
  uint u = __float_as_uint(f);
  return (u + 0x7FFFu + ((u >> 16) & 1u)) >> 16;
}
__device__ __forceinline__ uint pk2(float a, float b){
  return (bfr(a) & 0xFFFFu) | (bfr(b) << 16);
}
__device__ __forceinline__ bf16x8 asbf(uint4 u){
  union { uint4 u; bf16x8 b; } c; c.u = u; return c.b;
}

// ---------------- preprocessing: 2-phase LDS-histogram bucket sort ----------------

__global__ __launch_bounds__(256) void k_bucket(const int* __restrict__ ei,
    int* __restrict__ gcnt, uint* __restrict__ bedge){
  __shared__ uint   ent[NCH];    // src(17b) | d_local(8b)<<17
  __shared__ ushort bbs[NCH];    // bucket id
  __shared__ int    hist[NB];
  __shared__ int    fl[NB];
  __shared__ int    gb[NB];
  int t = threadIdx.x;
  int base = blockIdx.x * NCH;
  int nv = NE - base; if (nv > NCH) nv = NCH;
  for (int b = t; b < NB; b += 256){ hist[b] = 0; fl[b] = 0; }
  __syncthreads();
  for (int j = t; j < nv; j += 256){
    int i = base + j;                      // coalesced
    uint s = (uint)ei[i];
    uint d = (uint)ei[NE + i];
    uint b = __umulhi(d, BMAGIC);          // d / 200
    uint dl = d - b*BR;
    ent[j] = s | (dl << 17);
    bbs[j] = (ushort)b;
    atomicAdd(&hist[b], 1);
  }
  __syncthreads();
  for (int b = t; b < NB; b += 256){
    int h = hist[b];
    gb[b] = h ? atomicAdd(&gcnt[b*16], h) : 0;   // bulk reservation
  }
  __syncthreads();
  for (int j = t; j < nv; j += 256){
    uint b = bbs[j];
    int q = atomicAdd(&fl[b], 1);          // LDS fill
    bedge[(size_t)b*BCAP + gb[b] + q] = ent[j];
  }
}

// single-block exclusive scan of bucket totals (incl. +BR self-loops each)
__global__ __launch_bounds__(512) void k_bscan(const int* __restrict__ gcnt, int* __restrict__ bbase){
  __shared__ int s[512];
  int t = threadIdx.x;
  int v = (t < NB) ? (gcnt[t*16] + BR) : 0;
  s[t] = v;
  __syncthreads();
  for (int off = 1; off < 512; off <<= 1){
    int a = (t >= off) ? s[t-off] : 0;
    __syncthreads();
    s[t] += a;
    __syncthreads();
  }
  if (t < NB) bbase[t] = s[t] - v;
}

// fused per-bucket CSR build: LDS count + scan -> dis/rowptr/es (es = plain src)
__global__ __launch_bounds__(256) void k_build(const int* __restrict__ gcnt,
    const int* __restrict__ bbase, const uint* __restrict__ bedge,
    float* __restrict__ dis, int* __restrict__ rowptr, uint* __restrict__ es){
  __shared__ uint eL[BCAP];
  __shared__ int  cl[BR];
  __shared__ int  fl[BR];
  __shared__ int  pf[256];
  int b = blockIdx.x, t = threadIdx.x;
  int base = bbase[b];
  if (t < BR){ cl[t] = 0; fl[t] = 0; }
  __syncthreads();
  int cnt = gcnt[b*16];
  for (int e = t; e < cnt; e += 256){
    uint u = bedge[(size_t)b*BCAP + e];
    eL[e] = u;
    atomicAdd(&cl[u >> 17], 1);
  }
  __syncthreads();
  // inclusive scan over (cl[i]+1)
  int v = (t < BR) ? (cl[t] + 1) : 0;
  pf[t] = v;
  __syncthreads();
  for (int off = 1; off < 256; off <<= 1){
    int a = (t >= off) ? pf[t-off] : 0;
    __syncthreads();
    pf[t] += a;
    __syncthreads();
  }
  if (t < BR){
    int n  = b*BR + t;
    int p0 = base + pf[t] - v;             // exclusive prefix (globally monotone)
    rowptr[n] = p0;
    dis[n] = rsqrtf((float)(cl[t] + 1));
    es[p0 + cl[t]] = (uint)n;              // self-loop last
  }
  if (b == NB-1 && t == 0) rowptr[NN] = NT;
  __syncthreads();
  for (int e = t; e < cnt; e += 256){
    uint u = eL[e];
    int  dloc = u >> 17;
    int  q  = atomicAdd(&fl[dloc], 1);
    int  p0 = base + pf[dloc] - (cl[dloc] + 1);
    es[p0 + q] = u & 0x1FFFFu;
  }
}

// ---------------- weight transpose: Wt[n][k] = bf16(W[k][n]), packed 2/uint ----------------
// block 0 -> W1, block 1 -> W2. thread t: out row n=t>>1, k-half (t&1)*64.
__global__ __launch_bounds__(256) void k_wt(const float* __restrict__ W1f, const float* __restrict__ W2f,
    uint* __restrict__ Wt1, uint* __restrict__ Wt2){
  const float* W = blockIdx.x ? W2f : W1f;
  uint* Wt = blockIdx.x ? Wt2 : Wt1;
  int t = threadIdx.x;
  int n = t >> 1, k0 = (t & 1) * 64;
  for (int kk = 0; kk < 64; kk += 2){
    float v0 = W[(size_t)(k0+kk  )*DD + n];
    float v1 = W[(size_t)(k0+kk+1)*DD + n];
    Wt[(size_t)n*64 + ((k0+kk)>>1)] = pk2(v0, v1);
  }
}

// ---------------- MFMA GEMM -> dis-scaled bf16: Y[r] = bf16(dis[r] * (X@W)[r]) ----------------
// Zero-LDS design. A-operand = Wt rows (cols of W), B-operand = X rows.
// D[n][r]: n = (lane>>4)*4+reg (HW-verified C/D layout), r = lane&15
// -> each lane owns ONE output row r; epilogue = lane-uniform dis scale + uint2 stores.
// A/B frags both packed with k = (lane>>4)*8 + j convention; MFMA result is
// invariant to the HW's internal k-permutation as long as A and B match.
// Block = 4 waves x 16 rows = 64 rows; per wave 8 col-tiles x 4 k-steps = 32 MFMAs.
template<int IN_BF16>
__global__ __launch_bounds__(256) void k_gemm(const void* __restrict__ Xv,
    const uint* __restrict__ Wt, const float* __restrict__ dis,
    uint* __restrict__ Y, int nrows){
  int t = threadIdx.x;
  int wv = t >> 6, l = t & 63;
  int g = l >> 4, li = l & 15;
  int r = blockIdx.x*64 + wv*16 + li;     // this lane's X/output row
  bool valid = (r < nrows);

  f32x4 acc[8];
  #pragma unroll
  for (int i = 0; i < 8; ++i) acc[i] = (f32x4){0.f,0.f,0.f,0.f};

  #pragma unroll
  for (int ks = 0; ks < 4; ++ks){
    int k0 = ks*32 + g*8;                 // this lane's 8-element k-chunk
    uint4 xb;
    if (IN_BF16){
      xb = valid ? ((const uint4*)Xv)[(size_t)r*16 + (k0>>3)] : make_uint4(0,0,0,0);
    } else {
      if (valid){
        const float* X = (const float*)Xv;
        float4 f0 = ((const float4*)X)[(size_t)r*32 + (k0>>2)];
        float4 f1 = ((const float4*)X)[(size_t)r*32 + (k0>>2) + 1];
        xb.x = pk2(f0.x, f0.y); xb.y = pk2(f0.z, f0.w);
        xb.z = pk2(f1.x, f1.y); xb.w = pk2(f1.z, f1.w);
      } else xb = make_uint4(0,0,0,0);
    }
    bf16x8 bfrag = asbf(xb);
    #pragma unroll
    for (int nt = 0; nt < 8; ++nt){
      uint4 wa = ((const uint4*)Wt)[(size_t)(nt*16 + li)*16 + (k0>>3)];
      acc[nt] = __builtin_amdgcn_mfma_f32_16x16x32_bf16(asbf(wa), bfrag, acc[nt], 0, 0, 0);
    }
  }
  if (valid){
    float dr = dis[r];
    #pragma unroll
    for (int nt = 0; nt < 8; ++nt){
      // lane holds cols n = nt*16 + g*4 + {0..3} of row r
      uint2 o;
      o.x = pk2(acc[nt][0]*dr, acc[nt][1]*dr);
      o.y = pk2(acc[nt][2]*dr, acc[nt][3]*dr);
      *(uint2*)&Y[(size_t)r*64 + nt*8 + g*2] = o;
    }
  }
}

// ---------------- CSR aggregation + bias + ELU ----------------
// out[n] = elu(dis[n] * sum_{s in N(n)} H'[s] + b); H' rows pre-scaled by dis[s].
// one WAVE per node (4 nodes / 256-thread block); lane = bf16 channel pair;
// 16x edge unroll -> 16 gathers in flight per wave.
template<int OUT_BF16>
__global__ __launch_bounds__(256) void k_agg(const uint* __restrict__ H,
    const int* __restrict__ rowptr, const float* __restrict__ dis,
    const uint* __restrict__ es, const float* __restrict__ bias,
    void* __restrict__ outv){
  int wid  = threadIdx.x >> 6;
  int lane = threadIdx.x & 63;
  int n = blockIdx.x*4 + wid;            // grid*4 == NN exactly
  int e0 = rowptr[n];
  int e1 = rowptr[n+1];
  float a0 = 0.f, a1 = 0.f, a2 = 0.f, a3 = 0.f;
  int e = e0;

#define ASTEP(k,A,B) { uint s##k = es[e+k]; \
    uint h##k = H[(size_t)s##k*64 + lane]; \
    A += __uint_as_float(h##k << 16); \
    B += __uint_as_float(h##k & 0xFFFF0000u); }

  for (; e + 16 <= e1; e += 16){
    ASTEP( 0,a0,a1) ASTEP( 1,a2,a3) ASTEP( 2,a0,a1) ASTEP( 3,a2,a3)
    ASTEP( 4,a0,a1) ASTEP( 5,a2,a3) ASTEP( 6,a0,a1) ASTEP( 7,a2,a3)
    ASTEP( 8,a0,a1) ASTEP( 9,a2,a3) ASTEP(10,a0,a1) ASTEP(11,a2,a3)
    ASTEP(12,a0,a1) ASTEP(13,a2,a3) ASTEP(14,a0,a1) ASTEP(15,a2,a3)
  }
  for (; e + 4 <= e1; e += 4){
    ASTEP(0,a0,a1) ASTEP(1,a2,a3) ASTEP(2,a0,a1) ASTEP(3,a2,a3)
  }
  for (; e < e1; ++e){
    ASTEP(0,a0,a1)
  }
#undef ASTEP

  float dn = dis[n];
  float2 b = *(const float2*)&bias[lane*2];
  float v0 = fmaf(dn, a0 + a2, b.x);
  float v1 = fmaf(dn, a1 + a3, b.y);
  v0 = (v0 > 0.f) ? v0 : expm1f(v0);
  v1 = (v1 > 0.f) ? v1 : expm1f(v1);
  if (OUT_BF16){
    ((uint*)outv)[(size_t)n*64 + lane] = pk2(v0, v1);
  } else {
    float2 o; o.x = v0; o.y = v1;
    *(float2*)&((float*)outv)[(size_t)n*DD + lane*2] = o;
  }
}

// ---------------- launch ----------------

extern "C" void kernel_launch(void* const* d_in, const int* in_sizes, int n_in,
                              void* d_out, int out_size, void* d_ws, size_t ws_size,
                              hipStream_t stream){
  const float* x  = (const float*)d_in[0];
  const int*   ei = (const int*)d_in[1];   // [2, NE]: src row then dst row
  const float* W1 = (const float*)d_in[2];
  const float* b1 = (const float*)d_in[3];
  const float* W2 = (const float*)d_in[4];
  const float* b2 = (const float*)d_in[5];

  // workspace carve-up (int units), every region 64-int (256B) aligned.
  // H's 256B alignment is CRITICAL: misaligned 256B rows straddle an extra
  // 128B line -> +42% gather FETCH (measured across R4..R8).
  // bedge (8.2MB, dead after k_build) aliases H (written first by k_gemm<0>).
  int*   ws_i   = (int*)d_ws;
  int*   gcnt   = ws_i + 0;                 // [0, 8000)  500*16 padded counters
  int*   bbase  = ws_i + 8000;              // [8000, 8576)
  float* dis    = (float*)(ws_i + 8576);    // [8576, 108608)
  int*   rowptr = ws_i + 108608;            // [108608, 208704)
  uint*  Wt1    = (uint*)(ws_i + 208704);   // [208704, 216896)  128x128 bf16
  uint*  Wt2    = (uint*)(ws_i + 216896);   // [216896, 225088)
  uint*  es     = (uint*)(ws_i + 225088);   // [225088, 1925120)
  uint*  H      = (uint*)(ws_i + 1925120);  // [1925120, 8325120)  byte 7700480 %256==0
  uint*  bedge  = H;                        // alias: 500*4096 = 2048000 uints
  uint*  out1   = (uint*)(ws_i + 8325120);  // [8325120, 11525120)  byte %256==0
  // total 11525120 ints = 46.1 MB (ws proven >= 66 MB in R1/R2)

  hipMemsetAsync(gcnt, 0, 8000*sizeof(int), stream);

  k_wt    <<<2,   256, 0, stream>>>(W1, W2, Wt1, Wt2);
  k_bucket<<<NBK, 256, 0, stream>>>(ei, gcnt, bedge);
  k_bscan <<<1,   512, 0, stream>>>(gcnt, bbase);
  k_build <<<NB,  256, 0, stream>>>(gcnt, bbase, bedge, dis, rowptr, es);

  // layer 1: H = bf16(dis*(x@W1)) ; out1 = bf16(elu(dis*agg + b1))
  k_gemm<0><<<NBG,   256, 0, stream>>>(x, Wt1, dis, H, NN);
  k_agg<1> <<<25000, 256, 0, stream>>>(H, rowptr, dis, es, b1, out1);
  // layer 2: H = bf16(dis*(out1@W2)) ; out = elu(dis*agg + b2)
  k_gemm<1><<<NBG,   256, 0, stream>>>(out1, Wt2, dis, H, NN);
  k_agg<0> <<<25000, 256, 0, stream>>>(H, rowptr, dis, es, b2, d_out);
}

// Round 10
// 270.970 us; speedup vs baseline: 1.2728x; 1.0361x over previous
//
#include <hip/hip_runtime.h>
#include <math.h>

#define NN 100000
#define NE 1600000
#define NT (NE + NN)   // 1700000 edges incl. self-loops
#define DD 128
#define NB 500          // dst buckets
#define BR 200          // node range per bucket (NB*BR == NN)
#define BCAP 4096       // bucket capacity (mean 3200, sigma 56 -> 15.9 sigma headroom)
#define NCH 2048        // edges per k_bucket block
#define NBK 782         // ceil(NE/NCH)
#define NBG 1563        // ceil(NN/64) gemm blocks
#define BMAGIC 21474837u // ceil(2^32/200); exact for d < 100000

typedef unsigned int uint;
typedef unsigned short ushort;
typedef __attribute__((ext_vector_type(8))) short bf16x8;
typedef __attribute__((ext_vector_type(4))) float f32x4;

// round-to-nearest-even fp32 -> bf16 (16-bit payload in a uint)
__device__ __forceinline__ uint bfr(float f){
  uint u = __float_as_uint(f);
  return (u + 0x7FFFu + ((u >> 16) & 1u)) >> 16;
}
__device__ __forceinline__ uint pk2(float a, float b){
  return (bfr(a) & 0xFFFFu) | (bfr(b) << 16);
}
__device__ __forceinline__ bf16x8 asbf(uint4 u){
  union { uint4 u; bf16x8 b; } c; c.u = u; return c.b;
}

// ---------------- init: weight transpose (blocks 0,1) + gcnt zero (block 2) ----------------
// Wt[n][k] = bf16(W[k][n]), packed 2/uint. thread t: out row n=t>>1, k-half (t&1)*64.
__global__ __launch_bounds__(256) void k_init(const float* __restrict__ W1f, const float* __restrict__ W2f,
    uint* __restrict__ Wt1, uint* __restrict__ Wt2, int* __restrict__ gcnt){
  int t = threadIdx.x;
  if (blockIdx.x == 2){
    for (int i = t; i < 8000; i += 256) gcnt[i] = 0;
    return;
  }
  const float* W = blockIdx.x ? W2f : W1f;
  uint* Wt = blockIdx.x ? Wt2 : Wt1;
  int n = t >> 1, k0 = (t & 1) * 64;
  for (int kk = 0; kk < 64; kk += 2){
    float v0 = W[(size_t)(k0+kk  )*DD + n];
    float v1 = W[(size_t)(k0+kk+1)*DD + n];
    Wt[(size_t)n*64 + ((k0+kk)>>1)] = pk2(v0, v1);
  }
}

// ---------------- preprocessing: 2-phase LDS-histogram bucket sort ----------------

__global__ __launch_bounds__(256) void k_bucket(const int* __restrict__ ei,
    int* __restrict__ gcnt, uint* __restrict__ bedge){
  __shared__ uint   ent[NCH];    // src(17b) | d_local(8b)<<17
  __shared__ ushort bbs[NCH];    // bucket id
  __shared__ int    hist[NB];
  __shared__ int    fl[NB];
  __shared__ int    gb[NB];
  int t = threadIdx.x;
  int base = blockIdx.x * NCH;
  int nv = NE - base; if (nv > NCH) nv = NCH;
  for (int b = t; b < NB; b += 256){ hist[b] = 0; fl[b] = 0; }
  __syncthreads();
  for (int j = t; j < nv; j += 256){
    int i = base + j;                      // coalesced
    uint s = (uint)ei[i];
    uint d = (uint)ei[NE + i];
    uint b = __umulhi(d, BMAGIC);          // d / 200
    uint dl = d - b*BR;
    ent[j] = s | (dl << 17);
    bbs[j] = (ushort)b;
    atomicAdd(&hist[b], 1);
  }
  __syncthreads();
  for (int b = t; b < NB; b += 256){
    int h = hist[b];
    gb[b] = h ? atomicAdd(&gcnt[b*16], h) : 0;   // bulk reservation
  }
  __syncthreads();
  for (int j = t; j < nv; j += 256){
    uint b = bbs[j];
    int q = atomicAdd(&fl[b], 1);          // LDS fill
    bedge[(size_t)b*BCAP + gb[b] + q] = ent[j];
  }
}

// single-block exclusive scan of bucket totals (incl. +BR self-loops each)
__global__ __launch_bounds__(512) void k_bscan(const int* __restrict__ gcnt, int* __restrict__ bbase){
  __shared__ int s[512];
  int t = threadIdx.x;
  int v = (t < NB) ? (gcnt[t*16] + BR) : 0;
  s[t] = v;
  __syncthreads();
  for (int off = 1; off < 512; off <<= 1){
    int a = (t >= off) ? s[t-off] : 0;
    __syncthreads();
    s[t] += a;
    __syncthreads();
  }
  if (t < NB) bbase[t] = s[t] - v;
}

// fused per-bucket CSR build: LDS count + scan -> dis/rowptr/es (es = plain src)
__global__ __launch_bounds__(256) void k_build(const int* __restrict__ gcnt,
    const int* __restrict__ bbase, const uint* __restrict__ bedge,
    float* __restrict__ dis, int* __restrict__ rowptr, uint* __restrict__ es){
  __shared__ uint eL[BCAP];
  __shared__ int  cl[BR];
  __shared__ int  fl[BR];
  __shared__ int  pf[256];
  int b = blockIdx.x, t = threadIdx.x;
  int base = bbase[b];
  if (t < BR){ cl[t] = 0; fl[t] = 0; }
  __syncthreads();
  int cnt = gcnt[b*16];
  for (int e = t; e < cnt; e += 256){
    uint u = bedge[(size_t)b*BCAP + e];
    eL[e] = u;
    atomicAdd(&cl[u >> 17], 1);
  }
  __syncthreads();
  // inclusive scan over (cl[i]+1)
  int v = (t < BR) ? (cl[t] + 1) : 0;
  pf[t] = v;
  __syncthreads();
  for (int off = 1; off < 256; off <<= 1){
    int a = (t >= off) ? pf[t-off] : 0;
    __syncthreads();
    pf[t] += a;
    __syncthreads();
  }
  if (t < BR){
    int n  = b*BR + t;
    int p0 = base + pf[t] - v;             // exclusive prefix (globally monotone)
    rowptr[n] = p0;
    dis[n] = rsqrtf((float)(cl[t] + 1));
    es[p0 + cl[t]] = (uint)n;              // self-loop last
  }
  if (b == NB-1 && t == 0) rowptr[NN] = NT;
  __syncthreads();
  for (int e = t; e < cnt; e += 256){
    uint u = eL[e];
    int  dloc = u >> 17;
    int  q  = atomicAdd(&fl[dloc], 1);
    int  p0 = base + pf[dloc] - (cl[dloc] + 1);
    es[p0 + q] = u & 0x1FFFFu;
  }
}

// ---------------- MFMA GEMM -> dis-scaled bf16: Y[r] = bf16(dis[r] * (X@W)[r]) ----------------
// Zero-LDS. A = Wt rows (cols of W), B = X rows. D: lane owns output row r=lane&15,
// cols n = nt*16 + (lane>>4)*4 + reg (HW-verified C/D layout). A/B share the same
// k-packing so the HW k-permutation cancels. 4 waves x 16 rows = 64 rows/block.
__global__ __launch_bounds__(256) void k_gemm(const float* __restrict__ X,
    const uint* __restrict__ Wt, const float* __restrict__ dis,
    uint* __restrict__ Y, int nrows){
  int t = threadIdx.x;
  int wv = t >> 6, l = t & 63;
  int g = l >> 4, li = l & 15;
  int r = blockIdx.x*64 + wv*16 + li;     // this lane's X/output row
  bool valid = (r < nrows);

  f32x4 acc[8];
  #pragma unroll
  for (int i = 0; i < 8; ++i) acc[i] = (f32x4){0.f,0.f,0.f,0.f};

  #pragma unroll
  for (int ks = 0; ks < 4; ++ks){
    int k0 = ks*32 + g*8;                 // this lane's 8-element k-chunk
    uint4 xb;
    if (valid){
      float4 f0 = ((const float4*)X)[(size_t)r*32 + (k0>>2)];
      float4 f1 = ((const float4*)X)[(size_t)r*32 + (k0>>2) + 1];
      xb.x = pk2(f0.x, f0.y); xb.y = pk2(f0.z, f0.w);
      xb.z = pk2(f1.x, f1.y); xb.w = pk2(f1.z, f1.w);
    } else xb = make_uint4(0,0,0,0);
    bf16x8 bfrag = asbf(xb);
    #pragma unroll
    for (int nt = 0; nt < 8; ++nt){
      uint4 wa = ((const uint4*)Wt)[(size_t)(nt*16 + li)*16 + (k0>>3)];
      acc[nt] = __builtin_amdgcn_mfma_f32_16x16x32_bf16(asbf(wa), bfrag, acc[nt], 0, 0, 0);
    }
  }
  if (valid){
    float dr = dis[r];
    #pragma unroll
    for (int nt = 0; nt < 8; ++nt){
      uint2 o;
      o.x = pk2(acc[nt][0]*dr, acc[nt][1]*dr);
      o.y = pk2(acc[nt][2]*dr, acc[nt][3]*dr);
      *(uint2*)&Y[(size_t)r*64 + nt*8 + g*2] = o;
    }
  }
}

// ---------------- FUSED layer-1 agg + layer-2 GEMM ----------------
// Block = 16 nodes. Phase 1: each wave aggregates 4 nodes sequentially
// (64 lanes = bf16 channel pairs, 16x unroll), elu -> fp32 act rows in LDS.
// Phase 2: act[16][128] @ W2 via MFMA (wave -> 2 col-tiles), dis-scaled bf16 H2.
__global__ __launch_bounds__(256) void k_aggemm(const uint* __restrict__ H,
    const int* __restrict__ rowptr, const float* __restrict__ dis,
    const uint* __restrict__ es, const float* __restrict__ bias,
    const uint* __restrict__ Wt, uint* __restrict__ H2){
  __shared__ float act[16][132];          // +4 pad: float4-aligned rows, low conflict
  int t = threadIdx.x;
  int wv = t >> 6, lane = t & 63;
  int n0 = blockIdx.x * 16;               // grid*16 == NN exactly
  float2 bb = *(const float2*)&bias[lane*2];

  for (int j = 0; j < 4; ++j){
    int n = n0 + wv*4 + j;
    int e0 = rowptr[n], e1 = rowptr[n+1];
    float a0 = 0.f, a1 = 0.f, a2 = 0.f, a3 = 0.f;
    int e = e0;
#define GSTEP(k,A,B) { uint s##k = es[e+k]; \
    uint h##k = H[(size_t)s##k*64 + lane]; \
    A += __uint_as_float(h##k << 16); \
    B += __uint_as_float(h##k & 0xFFFF0000u); }
    for (; e + 16 <= e1; e += 16){
      GSTEP( 0,a0,a1) GSTEP( 1,a2,a3) GSTEP( 2,a0,a1) GSTEP( 3,a2,a3)
      GSTEP( 4,a0,a1) GSTEP( 5,a2,a3) GSTEP( 6,a0,a1) GSTEP( 7,a2,a3)
      GSTEP( 8,a0,a1) GSTEP( 9,a2,a3) GSTEP(10,a0,a1) GSTEP(11,a2,a3)
      GSTEP(12,a0,a1) GSTEP(13,a2,a3) GSTEP(14,a0,a1) GSTEP(15,a2,a3)
    }
    for (; e + 4 <= e1; e += 4){
      GSTEP(0,a0,a1) GSTEP(1,a2,a3) GSTEP(2,a0,a1) GSTEP(3,a2,a3)
    }
    for (; e < e1; ++e){
      GSTEP(0,a0,a1)
    }
#undef GSTEP
    float dn = dis[n];
    float v0 = fmaf(dn, a0 + a2, bb.x);
    float v1 = fmaf(dn, a1 + a3, bb.y);
    v0 = (v0 > 0.f) ? v0 : expm1f(v0);
    v1 = (v1 > 0.f) ? v1 : expm1f(v1);
    act[wv*4 + j][lane*2]     = v0;
    act[wv*4 + j][lane*2 + 1] = v1;
  }
  __syncthreads();

  // phase 2: rows act[li][:] x Wt col-tiles {2wv, 2wv+1}
  int g = lane >> 4, li = lane & 15;
  int nid = n0 + li;
  f32x4 acc0 = (f32x4){0.f,0.f,0.f,0.f};
  f32x4 acc1 = (f32x4){0.f,0.f,0.f,0.f};
  #pragma unroll
  for (int ks = 0; ks < 4; ++ks){
    int k0 = ks*32 + g*8;
    float4 f0 = *(const float4*)&act[li][k0];
    float4 f1 = *(const float4*)&act[li][k0 + 4];
    uint4 xb;
    xb.x = pk2(f0.x, f0.y); xb.y = pk2(f0.z, f0.w);
    xb.z = pk2(f1.x, f1.y); xb.w = pk2(f1.z, f1.w);
    bf16x8 bfrag = asbf(xb);
    int nt0 = wv*2;
    uint4 wa0 = ((const uint4*)Wt)[(size_t)(nt0*16 + li)*16 + (k0>>3)];
    uint4 wa1 = ((const uint4*)Wt)[(size_t)((nt0+1)*16 + li)*16 + (k0>>3)];
    acc0 = __builtin_amdgcn_mfma_f32_16x16x32_bf16(asbf(wa0), bfrag, acc0, 0, 0, 0);
    acc1 = __builtin_amdgcn_mfma_f32_16x16x32_bf16(asbf(wa1), bfrag, acc1, 0, 0, 0);
  }
  float dr = dis[nid];
  uint2 o;
  o.x = pk2(acc0[0]*dr, acc0[1]*dr);
  o.y = pk2(acc0[2]*dr, acc0[3]*dr);
  *(uint2*)&H2[(size_t)nid*64 + (wv*2)*8 + g*2] = o;
  o.x = pk2(acc1[0]*dr, acc1[1]*dr);
  o.y = pk2(acc1[2]*dr, acc1[3]*dr);
  *(uint2*)&H2[(size_t)nid*64 + (wv*2+1)*8 + g*2] = o;
}

// ---------------- final CSR aggregation + bias + ELU (fp32 out) ----------------
template<int OUT_BF16>
__global__ __launch_bounds__(256) void k_agg(const uint* __restrict__ H,
    const int* __restrict__ rowptr, const float* __restrict__ dis,
    const uint* __restrict__ es, const float* __restrict__ bias,
    void* __restrict__ outv){
  int wid  = threadIdx.x >> 6;
  int lane = threadIdx.x & 63;
  int n = blockIdx.x*4 + wid;            // grid*4 == NN exactly
  int e0 = rowptr[n];
  int e1 = rowptr[n+1];
  float a0 = 0.f, a1 = 0.f, a2 = 0.f, a3 = 0.f;
  int e = e0;

#define ASTEP(k,A,B) { uint s##k = es[e+k]; \
    uint h##k = H[(size_t)s##k*64 + lane]; \
    A += __uint_as_float(h##k << 16); \
    B += __uint_as_float(h##k & 0xFFFF0000u); }

  for (; e + 16 <= e1; e += 16){
    ASTEP( 0,a0,a1) ASTEP( 1,a2,a3) ASTEP( 2,a0,a1) ASTEP( 3,a2,a3)
    ASTEP( 4,a0,a1) ASTEP( 5,a2,a3) ASTEP( 6,a0,a1) ASTEP( 7,a2,a3)
    ASTEP( 8,a0,a1) ASTEP( 9,a2,a3) ASTEP(10,a0,a1) ASTEP(11,a2,a3)
    ASTEP(12,a0,a1) ASTEP(13,a2,a3) ASTEP(14,a0,a1) ASTEP(15,a2,a3)
  }
  for (; e + 4 <= e1; e += 4){
    ASTEP(0,a0,a1) ASTEP(1,a2,a3) ASTEP(2,a0,a1) ASTEP(3,a2,a3)
  }
  for (; e < e1; ++e){
    ASTEP(0,a0,a1)
  }
#undef ASTEP

  float dn = dis[n];
  float2 b = *(const float2*)&bias[lane*2];
  float v0 = fmaf(dn, a0 + a2, b.x);
  float v1 = fmaf(dn, a1 + a3, b.y);
  v0 = (v0 > 0.f) ? v0 : expm1f(v0);
  v1 = (v1 > 0.f) ? v1 : expm1f(v1);
  if (OUT_BF16){
    ((uint*)outv)[(size_t)n*64 + lane] = pk2(v0, v1);
  } else {
    float2 o; o.x = v0; o.y = v1;
    *(float2*)&((float*)outv)[(size_t)n*DD + lane*2] = o;
  }
}

// ---------------- launch ----------------

extern "C" void kernel_launch(void* const* d_in, const int* in_sizes, int n_in,
                              void* d_out, int out_size, void* d_ws, size_t ws_size,
                              hipStream_t stream){
  const float* x  = (const float*)d_in[0];
  const int*   ei = (const int*)d_in[1];   // [2, NE]: src row then dst row
  const float* W1 = (const float*)d_in[2];
  const float* b1 = (const float*)d_in[3];
  const float* W2 = (const float*)d_in[4];
  const float* b2 = (const float*)d_in[5];

  // workspace carve-up (int units), every region 64-int (256B) aligned.
  // H/H2 256B alignment is CRITICAL: misaligned 256B rows straddle an extra
  // 128B line -> +42% gather FETCH (measured across R4..R8).
  // bedge (8.2MB, dead after k_build) aliases H (written first by k_gemm).
  int*   ws_i   = (int*)d_ws;
  int*   gcnt   = ws_i + 0;                 // [0, 8000)  500*16 padded counters
  int*   bbase  = ws_i + 8000;              // [8000, 8576)
  float* dis    = (float*)(ws_i + 8576);    // [8576, 108608)
  int*   rowptr = ws_i + 108608;            // [108608, 208704)  100001 used
  uint*  Wt1    = (uint*)(ws_i + 208704);   // [208704, 216896)  128x128 bf16
  uint*  Wt2    = (uint*)(ws_i + 216896);   // [216896, 225088)
  uint*  es     = (uint*)(ws_i + 225088);   // [225088, 1925120)  1700000 used
  uint*  H      = (uint*)(ws_i + 1925120);  // [1925120, 8325120)  6.4M uints, byte %256==0
  uint*  bedge  = H;                        // alias: 500*4096 = 2048000 uints
  uint*  H2     = (uint*)(ws_i + 8325120);  // [8325120, 14725120)  6.4M uints, byte %256==0
  // total 14725120 ints = 58.9 MB

  k_init  <<<3,   256, 0, stream>>>(W1, W2, Wt1, Wt2, gcnt);
  k_bucket<<<NBK, 256, 0, stream>>>(ei, gcnt, bedge);
  k_bscan <<<1,   512, 0, stream>>>(gcnt, bbase);
  k_build <<<NB,  256, 0, stream>>>(gcnt, bbase, bedge, dis, rowptr, es);

  // layer 1 GEMM: H = bf16(dis*(x@W1))
  k_gemm  <<<NBG,  256, 0, stream>>>(x, Wt1, dis, H, NN);
  // fused: act = elu(dis*agg(H) + b1); H2 = bf16(dis*(act@W2))
  k_aggemm<<<6250, 256, 0, stream>>>(H, rowptr, dis, es, b1, Wt2, H2);
  // final: out = elu(dis*agg(H2) + b2)
  k_agg<0><<<25000,256, 0, stream>>>(H2, rowptr, dis, es, b2, d_out);
}